// Round 15
// baseline (177.013 us; speedup 1.0000x reference)
//
#include <hip/hip_runtime.h>
#include <hip/hip_bf16.h>
#include <stdint.h>

// Problem dims
#define B_  16
#define T_  2048
#define D_  512
#define I_  1024
#define K_  31
#define M_  (B_ * T_)   // 32768

typedef __attribute__((ext_vector_type(8))) __bf16 bf16x8;
typedef __attribute__((ext_vector_type(4))) float  f32x4;
typedef __fp16 f16x2 __attribute__((ext_vector_type(2)));

__device__ __forceinline__ unsigned short f2bf(float f) {
    union { float f; uint32_t u; } v; v.f = f;
    uint32_t u = v.u;
    uint32_t r = (u + 0x7FFFu + ((u >> 16) & 1u)) >> 16;
    return (unsigned short)r;
}
__device__ __forceinline__ float bf2f(unsigned short h) {
    union { uint32_t u; float f; } v; v.u = ((uint32_t)h) << 16;
    return v.f;
}

__device__ __forceinline__ void gload_lds16(const void* g, void* l) {
    __builtin_amdgcn_global_load_lds(
        (const __attribute__((address_space(1))) unsigned int*)g,
        (__attribute__((address_space(3))) unsigned int*)l, 16, 0, 0);
}

// ---------------- fused: LayerNorm (bid < 8192) + weight cast (bid >= 8192)
__global__ __launch_bounds__(256) void ln_prep_kernel(
    const float* __restrict__ x, const float* __restrict__ gam,
    const float* __restrict__ bet, unsigned short* __restrict__ xn,
    const float* __restrict__ w1, const float* __restrict__ w2,
    unsigned short* __restrict__ w1b, unsigned short* __restrict__ w2b)
{
    if (blockIdx.x >= 8192) {
        int i = (blockIdx.x - 8192) * 256 + threadIdx.x;
        const int n1 = 2 * I_ * D_;   // 1048576
        const int n2 = D_ * I_;       // 524288
        if (i < n1) w1b[i] = f2bf(w1[i]);
        if (i < n2) w2b[i] = f2bf(w2[i]);
        return;
    }
    int row  = blockIdx.x * 4 + (threadIdx.x >> 6);
    int lane = threadIdx.x & 63;
    const float* xr = x + (size_t)row * D_ + lane * 8;
    float4 a0 = *(const float4*)xr;
    float4 a1 = *(const float4*)(xr + 4);
    float xs[8] = {a0.x, a0.y, a0.z, a0.w, a1.x, a1.y, a1.z, a1.w};

    float s = xs[0]+xs[1]+xs[2]+xs[3]+xs[4]+xs[5]+xs[6]+xs[7];
    #pragma unroll
    for (int off = 32; off; off >>= 1) s += __shfl_xor(s, off);
    float mu = s * (1.0f / D_);

    float q = 0.f;
    #pragma unroll
    for (int j = 0; j < 8; ++j) { float d = xs[j] - mu; q += d * d; }
    #pragma unroll
    for (int off = 32; off; off >>= 1) q += __shfl_xor(q, off);
    float rstd = rsqrtf(q * (1.0f / D_) + 1e-5f);

    float4 g0 = *(const float4*)(gam + lane * 8);
    float4 g1 = *(const float4*)(gam + lane * 8 + 4);
    float4 e0 = *(const float4*)(bet + lane * 8);
    float4 e1 = *(const float4*)(bet + lane * 8 + 4);
    float gs[8] = {g0.x, g0.y, g0.z, g0.w, g1.x, g1.y, g1.z, g1.w};
    float bs[8] = {e0.x, e0.y, e0.z, e0.w, e1.x, e1.y, e1.z, e1.w};

    unsigned short o[8];
    #pragma unroll
    for (int j = 0; j < 8; ++j) o[j] = f2bf((xs[j] - mu) * rstd * gs[j] + bs[j]);
    uint4 pk;
    pk.x = (uint32_t)o[0] | ((uint32_t)o[1] << 16);
    pk.y = (uint32_t)o[2] | ((uint32_t)o[3] << 16);
    pk.z = (uint32_t)o[4] | ((uint32_t)o[5] << 16);
    pk.w = (uint32_t)o[6] | ((uint32_t)o[7] << 16);
    *(uint4*)(xn + (size_t)row * D_ + lane * 8) = pk;
}

// ======================================================================
// 256x256-class GEMM engine, 2 barriers per K-tile (KTILE2) — R6-proven.
// FROZEN (R7-R9: every reordering regressed 8-20%).
// ======================================================================

#define VMCNT(n) asm volatile("s_waitcnt vmcnt(" #n ")" ::: "memory")

#define RD(base, idx) (*(const bf16x8*)(lds + (base) + (idx) * 2048))
#define MF(m, n, a, b) \
    acc[m][n] = __builtin_amdgcn_mfma_f32_16x16x32_bf16(a, b, acc[m][n], 0, 0, 0)
#define MFQ(MB, x0, x1, x2, x3, c0, c1, c2, c3) do { \
    MF(MB+0,0,x0,c0); MF(MB+0,1,x0,c1); MF(MB+0,2,x0,c2); MF(MB+0,3,x0,c3); \
    MF(MB+1,0,x1,c0); MF(MB+1,1,x1,c1); MF(MB+1,2,x1,c2); MF(MB+1,3,x1,c3); \
    MF(MB+2,0,x2,c0); MF(MB+2,1,x2,c1); MF(MB+2,2,x2,c2); MF(MB+2,3,x2,c3); \
    MF(MB+3,0,x3,c0); MF(MB+3,1,x3,c1); MF(MB+3,2,x3,c2); MF(MB+3,3,x3,c3); \
} while (0)

#define ISSUE_A(j, c) do { \
    gload_lds16(agA[j], lds + (c) * 65536 + tid * 16 + (j) * 8192); \
    agA[j] += 64; } while (0)
#define ISSUE_B(j, c) do { \
    gload_lds16(agB[j], lds + (c) * 65536 + 32768 + tid * 16 + (j) * 8192); \
    agB[j] += 64; } while (0)
#define ISSUE6(c) do { ISSUE_B(0,c); ISSUE_B(1,c); ISSUE_B(2,c); ISSUE_B(3,c); \
                       ISSUE_A(0,c); ISSUE_A(2,c); } while (0)
#define ISSUE2(c) do { ISSUE_A(1,c); ISSUE_A(3,c); } while (0)

#define LGKM_SCHED() do { \
    asm volatile("s_waitcnt lgkmcnt(0)" ::: "memory"); \
    __builtin_amdgcn_sched_barrier(0); } while (0)

#define KTILE2(CUR, NXT, DOISS) do { \
    bf16x8 b0,b1,b2,b3, x0,x1,x2,x3; \
    b0 = RD(bB0[CUR],0); b1 = RD(bB0[CUR],1); b2 = RD(bB0[CUR],2); b3 = RD(bB0[CUR],3); \
    x0 = RD(bA0[CUR],0); x1 = RD(bA0[CUR],1); x2 = RD(bA0[CUR],2); x3 = RD(bA0[CUR],3); \
    if (DOISS) { ISSUE6(NXT); } \
    __builtin_amdgcn_s_setprio(1); \
    MFQ(0, x0,x1,x2,x3, b0,b1,b2,b3); \
    __builtin_amdgcn_s_setprio(0); \
    LGKM_SCHED(); \
    if (DOISS) { VMCNT(6); } else { VMCNT(0); } \
    __builtin_amdgcn_s_barrier(); \
    x0 = RD(bA0[CUR],4); x1 = RD(bA0[CUR],5); x2 = RD(bA0[CUR],6); x3 = RD(bA0[CUR],7); \
    if (DOISS) { ISSUE2(NXT); } \
    __builtin_amdgcn_s_setprio(1); \
    MFQ(4, x0,x1,x2,x3, b0,b1,b2,b3); \
    __builtin_amdgcn_s_setprio(0); \
    b0 = RD(bB1[CUR],0); b1 = RD(bB1[CUR],1); b2 = RD(bB1[CUR],2); b3 = RD(bB1[CUR],3); \
    x0 = RD(bA1[CUR],0); x1 = RD(bA1[CUR],1); x2 = RD(bA1[CUR],2); x3 = RD(bA1[CUR],3); \
    __builtin_amdgcn_s_setprio(1); \
    MFQ(0, x0,x1,x2,x3, b0,b1,b2,b3); \
    __builtin_amdgcn_s_setprio(0); \
    x0 = RD(bA1[CUR],4); x1 = RD(bA1[CUR],5); x2 = RD(bA1[CUR],6); x3 = RD(bA1[CUR],7); \
    __builtin_amdgcn_s_setprio(1); \
    MFQ(4, x0,x1,x2,x3, b0,b1,b2,b3); \
    __builtin_amdgcn_s_setprio(0); \
    LGKM_SCHED(); \
    if (DOISS) { VMCNT(2); } \
    __builtin_amdgcn_s_barrier(); \
} while (0)

// ---------------- GEMM1: 2x512 blocks (split for per-kernel profiling),
// one 256-row x 128-channel tile each. Mapping identical to the 1024-block
// launch via `base` offset.
__global__ __launch_bounds__(512, 2) void gemm1_kernel(
    const unsigned short* __restrict__ xn,
    const unsigned short* __restrict__ w1b,
    const float* __restrict__ b1,
    unsigned short* __restrict__ u,
    int base)
{
    __shared__ __align__(16) unsigned char lds[131072];
    const int tid  = threadIdx.x;
    const int lane = tid & 63;
    const int wv   = tid >> 6;
    const int wm   = wv >> 2;   // 0..1
    const int wn   = wv & 3;    // 0..3

    const int bid = base + blockIdx.x;          // nwg = 1024 overall
    const int sw  = (bid & 7) * 128 + (bid >> 3);
    const int jb  = sw & 7;
    const int m0  = (sw >> 3) * 256;

    const unsigned short* agA[4];
    const unsigned short* agB[4];
    {
        const int srow = tid >> 3;
        const int scb  = tid & 7;
        #pragma unroll
        for (int j = 0; j < 4; ++j) {
            int row = j * 64 + srow;
            int kk  = (scb ^ (row & 7)) * 8;
            agA[j] = xn + (size_t)(m0 + row) * D_ + kk;
            int chl  = ((row >> 5) << 4) + (row & 15);
            int wrow = ((row & 16) ? 1024 : 0) + jb * 128 + chl;
            agB[j] = w1b + (size_t)wrow * D_ + kk;
        }
    }

    const int l15 = lane & 15;
    const unsigned kq  = (unsigned)((lane >> 4) << 4);
    const unsigned swx = (unsigned)((l15 & 7) << 4);
    const unsigned rA  = (unsigned)(wm * 128 + l15) * 128;
    const unsigned rB  = 32768u + (unsigned)(wn * 64 + l15) * 128;
    const unsigned bA0[2] = {rA + (kq ^ swx),          rA + (kq ^ swx) + 65536u};
    const unsigned bA1[2] = {rA + ((64u + kq) ^ swx),  rA + ((64u + kq) ^ swx) + 65536u};
    const unsigned bB0[2] = {rB + (kq ^ swx),          rB + (kq ^ swx) + 65536u};
    const unsigned bB1[2] = {rB + ((64u + kq) ^ swx),  rB + ((64u + kq) ^ swx) + 65536u};

    f32x4 acc[8][4];
    #pragma unroll
    for (int i = 0; i < 8; ++i)
        #pragma unroll
        for (int n = 0; n < 4; ++n) acc[i][n] = (f32x4){0.f, 0.f, 0.f, 0.f};

    ISSUE6(0); ISSUE2(0);
    VMCNT(2);
    __builtin_amdgcn_s_barrier();

    // NT = 8 K-tiles
    #pragma unroll 1
    for (int h = 0; h < 3; ++h) {               // kt 0..5
        KTILE2(0, 1, true);
        KTILE2(1, 0, true);
    }
    KTILE2(0, 1, true);                          // kt 6 (stages kt7)
    KTILE2(1, 0, false);                         // kt 7

    // epilogue: SwiGLU, frag-local a/g pairing
    const int rQ = (lane >> 4) * 4;
    #pragma unroll
    for (int p = 0; p < 2; ++p) {
        int ch = jb * 128 + wn * 32 + p * 16 + l15;
        float ba = b1[ch];
        float bg = b1[1024 + ch];
        #pragma unroll
        for (int mf = 0; mf < 8; ++mf) {
            #pragma unroll
            for (int r = 0; r < 4; ++r) {
                float a = acc[mf][2 * p][r] + ba;
                float g = acc[mf][2 * p + 1][r] + bg;
                float sg = g * __builtin_amdgcn_rcpf(1.0f + __expf(-g));
                int row = m0 + wm * 128 + mf * 16 + rQ + r;
                u[(size_t)row * I_ + ch] = f2bf(a * sg);
            }
        }
    }
}

// ---------------- depthwise conv K=31 + bias + PReLU: u bf16 -> v bf16 ----
// R12 geometry+staging (transposed LDS, 256-t tile, 2048 blocks), fdot2
// compute (R14, proven equal to R12; kept).
#define SUTS 292
__global__ __launch_bounds__(256, 4) void dwconv_kernel(
    const unsigned short* __restrict__ u, const float* __restrict__ dw,
    const float* __restrict__ dwb, const float* __restrict__ alpha,
    unsigned short* __restrict__ v)
{
    // grid: x = T/256 = 8, y = I/64 = 16, z = B = 16
    __shared__ __align__(8) unsigned short sut[64 * SUTS];   // 37376 B
    const int tid = threadIdx.x;
    const int c0  = blockIdx.y * 64;
    const int b   = blockIdx.z;
    const int t0  = blockIdx.x * 256;

    // stage + transpose: j in [0,286), t = t0-15+j, zero-filled halo
    #pragma unroll
    for (int it = 0; it < 9; ++it) {
        int r = it * 32 + (tid >> 3);
        if (r < 286) {
            int tt = t0 - 15 + r;
            int cc = (tid & 7) * 8;
            uint4 val = {0u, 0u, 0u, 0u};
            if (tt >= 0 && tt < T_)
                val = *(const uint4*)(u + ((size_t)b * T_ + tt) * I_ + c0 + cc);
            unsigned short e[8];
            *(uint4*)e = val;
            #pragma unroll
            for (int jj = 0; jj < 8; ++jj)
                sut[(cc + jj) * SUTS + r] = e[jj];
        }
    }
    __syncthreads();

    const int c  = tid & 63;
    const int tb = (tid >> 6) * 64;   // 64 outputs per thread

    // dw -> f16 pairs (16 pairs; last = (dw[30], 0))
    f16x2 dwp[16];
    {
        const float* dwc = dw + (size_t)(c0 + c) * K_;
        #pragma unroll
        for (int m = 0; m < 15; ++m)
            dwp[m] = __builtin_amdgcn_cvt_pkrtz(dwc[2 * m], dwc[2 * m + 1]);
        dwp[15] = __builtin_amdgcn_cvt_pkrtz(dwc[30], 0.0f);
    }
    const float bia = dwb[c0 + c], al = alpha[c0 + c];

    const unsigned short* srow = sut + c * SUTS;
    unsigned short* vb = v + ((size_t)b * T_ + t0 + tb) * I_ + c0 + c;

    #pragma unroll
    for (int chk = 0; chk < 4; ++chk) {
        const int o = tb + chk * 16;           // window j in [o, o+48)
        uint32_t pkEu[24];
        #pragma unroll
        for (int q = 0; q < 12; ++q) {
            uint2 d = *(const uint2*)(srow + o + q * 4);
            union { uint32_t u; float f; } lo, hi;
            lo.u = d.x << 16; hi.u = d.x & 0xFFFF0000u;
            pkEu[2 * q] = __builtin_bit_cast(uint32_t,
                __builtin_amdgcn_cvt_pkrtz(lo.f, hi.f));
            lo.u = d.y << 16; hi.u = d.y & 0xFFFF0000u;
            pkEu[2 * q + 1] = __builtin_bit_cast(uint32_t,
                __builtin_amdgcn_cvt_pkrtz(lo.f, hi.f));
        }
        uint32_t pkOu[23];
        #pragma unroll
        for (int q = 0; q < 23; ++q)
            pkOu[q] = (pkEu[q] >> 16) | (pkEu[q + 1] << 16);

        #pragma unroll
        for (int i = 0; i < 16; ++i) {
            float acc = bia;
            const int e = i >> 1;
            #pragma unroll
            for (int m = 0; m < 16; ++m) {
                uint32_t wv = (i & 1) ? pkOu[e + m] : pkEu[e + m];
                acc = __builtin_amdgcn_fdot2(
                    __builtin_bit_cast(f16x2, wv), dwp[m], acc, false);
            }
            float ov = acc > 0.f ? acc : al * acc;
            vb[(size_t)(chk * 16 + i) * I_] = f2bf(ov);
        }
    }
}

// ---------------- GEMM2: v[32768,1024] x w2b^T + b2 -> out fp32 [32768,512] ----------------
__global__ __launch_bounds__(512, 2) void gemm2_kernel(
    const unsigned short* __restrict__ v,
    const unsigned short* __restrict__ w2b,
    const float* __restrict__ b2,
    float* __restrict__ out)
{
    __shared__ __align__(16) unsigned char lds[131072];
    const int tid  = threadIdx.x;
    const int lane = tid & 63;
    const int wv   = tid >> 6;
    const int wm   = wv >> 2;
    const int wn   = wv & 3;

    const int bid = blockIdx.x;                 // 256 blocks
    const int sw  = (bid & 7) * 32 + (bid >> 3);
    const int n0  = (sw & 1) * 256;
    const int m0  = (sw >> 1) * 256;

    const unsigned short* agA[4];
    const unsigned short* agB[4];
    {
        const int srow = tid >> 3;
        const int scb  = tid & 7;
        #pragma unroll
        for (int j = 0; j < 4; ++j) {
            int row = j * 64 + srow;
            int kk  = (scb ^ (row & 7)) * 8;
            agA[j] = v   + (size_t)(m0 + row) * I_ + kk;
            agB[j] = w2b + (size_t)(n0 + row) * I_ + kk;
        }
    }

    const int l15 = lane & 15;
    const unsigned kq  = (unsigned)((lane >> 4) << 4);
    const unsigned swx = (unsigned)((l15 & 7) << 4);
    const unsigned rA  = (unsigned)(wm * 128 + l15) * 128;
    const unsigned rB  = 32768u + (unsigned)(wn * 64 + l15) * 128;
    const unsigned bA0[2] = {rA + (kq ^ swx),          rA + (kq ^ swx) + 65536u};
    const unsigned bA1[2] = {rA + ((64u + kq) ^ swx),  rA + ((64u + kq) ^ swx) + 65536u};
    const unsigned bB0[2] = {rB + (kq ^ swx),          rB + (kq ^ swx) + 65536u};
    const unsigned bB1[2] = {rB + ((64u + kq) ^ swx),  rB + ((64u + kq) ^ swx) + 65536u};

    f32x4 acc[8][4];
    #pragma unroll
    for (int i = 0; i < 8; ++i)
        #pragma unroll
        for (int n = 0; n < 4; ++n) acc[i][n] = (f32x4){0.f, 0.f, 0.f, 0.f};

    ISSUE6(0); ISSUE2(0);
    VMCNT(2);
    __builtin_amdgcn_s_barrier();

    // NT = 16 K-tiles
    #pragma unroll 1
    for (int h = 0; h < 7; ++h) {               // kt 0..13
        KTILE2(0, 1, true);
        KTILE2(1, 0, true);
    }
    KTILE2(0, 1, true);                          // kt 14
    KTILE2(1, 0, false);                         // kt 15

    const int rQ = (lane >> 4) * 4;
    #pragma unroll
    for (int nf = 0; nf < 4; ++nf) {
        int col = n0 + wn * 64 + nf * 16 + l15;
        float bb = b2[col];
        #pragma unroll
        for (int mf = 0; mf < 8; ++mf) {
            #pragma unroll
            for (int r = 0; r < 4; ++r) {
                int row = m0 + wm * 128 + mf * 16 + rQ + r;
                out[(size_t)row * D_ + col] = acc[mf][nf][r] + bb;
            }
        }
    }
}

extern "C" void kernel_launch(void* const* d_in, const int* in_sizes, int n_in,
                              void* d_out, int out_size, void* d_ws, size_t ws_size,
                              hipStream_t stream) {
    const float* x     = (const float*)d_in[0];
    const float* ln_g  = (const float*)d_in[1];
    const float* ln_b  = (const float*)d_in[2];
    const float* w1    = (const float*)d_in[3];
    const float* b1    = (const float*)d_in[4];
    const float* dw    = (const float*)d_in[5];
    const float* dwb   = (const float*)d_in[6];
    const float* alpha = (const float*)d_in[7];
    const float* w2    = (const float*)d_in[8];
    const float* b2    = (const float*)d_in[9];
    float* out = (float*)d_out;

    char* ws = (char*)d_ws;
    unsigned short* xn  = (unsigned short*)(ws);                 // 32 MB
    unsigned short* u   = (unsigned short*)(ws + 33554432);      // 64 MB
    unsigned short* v   = (unsigned short*)(ws + 100663296);     // 64 MB
    unsigned short* w1b = (unsigned short*)(ws + 167772160);     // 2 MB
    unsigned short* w2b = (unsigned short*)(ws + 169869312);     // 1 MB

    ln_prep_kernel<<<12288, 256, 0, stream>>>(x, ln_g, ln_b, xn, w1, w2, w1b, w2b);
    gemm1_kernel<<<512, 512, 0, stream>>>(xn, w1b, b1, u, 0);
    gemm1_kernel<<<512, 512, 0, stream>>>(xn, w1b, b1, u, 512);
    dim3 gc(T_ / 256, I_ / 64, B_);           // (8, 16, 16)
    dwconv_kernel<<<gc, 256, 0, stream>>>(u, dw, dwb, alpha, v);
    gemm2_kernel<<<256, 512, 0, stream>>>(v, w2b, b2, out);
}

// Round 16
// 176.008 us; speedup vs baseline: 1.0057x; 1.0057x over previous
//
#include <hip/hip_runtime.h>
#include <hip/hip_bf16.h>
#include <stdint.h>

// Problem dims
#define B_  16
#define T_  2048
#define D_  512
#define I_  1024
#define K_  31
#define M_  (B_ * T_)   // 32768

typedef __attribute__((ext_vector_type(8))) __bf16 bf16x8;
typedef __attribute__((ext_vector_type(4))) float  f32x4;
typedef __fp16 f16x2 __attribute__((ext_vector_type(2)));

__device__ __forceinline__ unsigned short f2bf(float f) {
    union { float f; uint32_t u; } v; v.f = f;
    uint32_t u = v.u;
    uint32_t r = (u + 0x7FFFu + ((u >> 16) & 1u)) >> 16;
    return (unsigned short)r;
}
__device__ __forceinline__ float bf2f(unsigned short h) {
    union { uint32_t u; float f; } v; v.u = ((uint32_t)h) << 16;
    return v.f;
}

__device__ __forceinline__ void gload_lds16(const void* g, void* l) {
    __builtin_amdgcn_global_load_lds(
        (const __attribute__((address_space(1))) unsigned int*)g,
        (__attribute__((address_space(3))) unsigned int*)l, 16, 0, 0);
}

// ---------------- fused: LayerNorm (bid < 8192) + weight cast (bid >= 8192)
__global__ __launch_bounds__(256) void ln_prep_kernel(
    const float* __restrict__ x, const float* __restrict__ gam,
    const float* __restrict__ bet, unsigned short* __restrict__ xn,
    const float* __restrict__ w1, const float* __restrict__ w2,
    unsigned short* __restrict__ w1b, unsigned short* __restrict__ w2b)
{
    if (blockIdx.x >= 8192) {
        int i = (blockIdx.x - 8192) * 256 + threadIdx.x;
        const int n1 = 2 * I_ * D_;   // 1048576
        const int n2 = D_ * I_;       // 524288
        if (i < n1) w1b[i] = f2bf(w1[i]);
        if (i < n2) w2b[i] = f2bf(w2[i]);
        return;
    }
    int row  = blockIdx.x * 4 + (threadIdx.x >> 6);
    int lane = threadIdx.x & 63;
    const float* xr = x + (size_t)row * D_ + lane * 8;
    float4 a0 = *(const float4*)xr;
    float4 a1 = *(const float4*)(xr + 4);
    float xs[8] = {a0.x, a0.y, a0.z, a0.w, a1.x, a1.y, a1.z, a1.w};

    float s = xs[0]+xs[1]+xs[2]+xs[3]+xs[4]+xs[5]+xs[6]+xs[7];
    #pragma unroll
    for (int off = 32; off; off >>= 1) s += __shfl_xor(s, off);
    float mu = s * (1.0f / D_);

    float q = 0.f;
    #pragma unroll
    for (int j = 0; j < 8; ++j) { float d = xs[j] - mu; q += d * d; }
    #pragma unroll
    for (int off = 32; off; off >>= 1) q += __shfl_xor(q, off);
    float rstd = rsqrtf(q * (1.0f / D_) + 1e-5f);

    float4 g0 = *(const float4*)(gam + lane * 8);
    float4 g1 = *(const float4*)(gam + lane * 8 + 4);
    float4 e0 = *(const float4*)(bet + lane * 8);
    float4 e1 = *(const float4*)(bet + lane * 8 + 4);
    float gs[8] = {g0.x, g0.y, g0.z, g0.w, g1.x, g1.y, g1.z, g1.w};
    float bs[8] = {e0.x, e0.y, e0.z, e0.w, e1.x, e1.y, e1.z, e1.w};

    unsigned short o[8];
    #pragma unroll
    for (int j = 0; j < 8; ++j) o[j] = f2bf((xs[j] - mu) * rstd * gs[j] + bs[j]);
    uint4 pk;
    pk.x = (uint32_t)o[0] | ((uint32_t)o[1] << 16);
    pk.y = (uint32_t)o[2] | ((uint32_t)o[3] << 16);
    pk.z = (uint32_t)o[4] | ((uint32_t)o[5] << 16);
    pk.w = (uint32_t)o[6] | ((uint32_t)o[7] << 16);
    *(uint4*)(xn + (size_t)row * D_ + lane * 8) = pk;
}

// ======================================================================
// 256x256-class GEMM engine, 2 barriers per K-tile (KTILE2) — R6-proven.
// FROZEN (R7-R9: every reordering regressed 8-20%).
// ======================================================================

#define VMCNT(n) asm volatile("s_waitcnt vmcnt(" #n ")" ::: "memory")

#define RD(base, idx) (*(const bf16x8*)(lds + (base) + (idx) * 2048))
#define MF(m, n, a, b) \
    acc[m][n] = __builtin_amdgcn_mfma_f32_16x16x32_bf16(a, b, acc[m][n], 0, 0, 0)
#define MFQ(MB, x0, x1, x2, x3, c0, c1, c2, c3) do { \
    MF(MB+0,0,x0,c0); MF(MB+0,1,x0,c1); MF(MB+0,2,x0,c2); MF(MB+0,3,x0,c3); \
    MF(MB+1,0,x1,c0); MF(MB+1,1,x1,c1); MF(MB+1,2,x1,c2); MF(MB+1,3,x1,c3); \
    MF(MB+2,0,x2,c0); MF(MB+2,1,x2,c1); MF(MB+2,2,x2,c2); MF(MB+2,3,x2,c3); \
    MF(MB+3,0,x3,c0); MF(MB+3,1,x3,c1); MF(MB+3,2,x3,c2); MF(MB+3,3,x3,c3); \
} while (0)

#define ISSUE_A(j, c) do { \
    gload_lds16(agA[j], lds + (c) * 65536 + tid * 16 + (j) * 8192); \
    agA[j] += 64; } while (0)
#define ISSUE_B(j, c) do { \
    gload_lds16(agB[j], lds + (c) * 65536 + 32768 + tid * 16 + (j) * 8192); \
    agB[j] += 64; } while (0)
#define ISSUE6(c) do { ISSUE_B(0,c); ISSUE_B(1,c); ISSUE_B(2,c); ISSUE_B(3,c); \
                       ISSUE_A(0,c); ISSUE_A(2,c); } while (0)
#define ISSUE2(c) do { ISSUE_A(1,c); ISSUE_A(3,c); } while (0)

#define LGKM_SCHED() do { \
    asm volatile("s_waitcnt lgkmcnt(0)" ::: "memory"); \
    __builtin_amdgcn_sched_barrier(0); } while (0)

#define KTILE2(CUR, NXT, DOISS) do { \
    bf16x8 b0,b1,b2,b3, x0,x1,x2,x3; \
    b0 = RD(bB0[CUR],0); b1 = RD(bB0[CUR],1); b2 = RD(bB0[CUR],2); b3 = RD(bB0[CUR],3); \
    x0 = RD(bA0[CUR],0); x1 = RD(bA0[CUR],1); x2 = RD(bA0[CUR],2); x3 = RD(bA0[CUR],3); \
    if (DOISS) { ISSUE6(NXT); } \
    __builtin_amdgcn_s_setprio(1); \
    MFQ(0, x0,x1,x2,x3, b0,b1,b2,b3); \
    __builtin_amdgcn_s_setprio(0); \
    LGKM_SCHED(); \
    if (DOISS) { VMCNT(6); } else { VMCNT(0); } \
    __builtin_amdgcn_s_barrier(); \
    x0 = RD(bA0[CUR],4); x1 = RD(bA0[CUR],5); x2 = RD(bA0[CUR],6); x3 = RD(bA0[CUR],7); \
    if (DOISS) { ISSUE2(NXT); } \
    __builtin_amdgcn_s_setprio(1); \
    MFQ(4, x0,x1,x2,x3, b0,b1,b2,b3); \
    __builtin_amdgcn_s_setprio(0); \
    b0 = RD(bB1[CUR],0); b1 = RD(bB1[CUR],1); b2 = RD(bB1[CUR],2); b3 = RD(bB1[CUR],3); \
    x0 = RD(bA1[CUR],0); x1 = RD(bA1[CUR],1); x2 = RD(bA1[CUR],2); x3 = RD(bA1[CUR],3); \
    __builtin_amdgcn_s_setprio(1); \
    MFQ(0, x0,x1,x2,x3, b0,b1,b2,b3); \
    __builtin_amdgcn_s_setprio(0); \
    x0 = RD(bA1[CUR],4); x1 = RD(bA1[CUR],5); x2 = RD(bA1[CUR],6); x3 = RD(bA1[CUR],7); \
    __builtin_amdgcn_s_setprio(1); \
    MFQ(4, x0,x1,x2,x3, b0,b1,b2,b3); \
    __builtin_amdgcn_s_setprio(0); \
    LGKM_SCHED(); \
    if (DOISS) { VMCNT(2); } \
    __builtin_amdgcn_s_barrier(); \
} while (0)

// ---------------- GEMM1: 1024 blocks, one 256-row x 128-channel tile each.
__global__ __launch_bounds__(512, 2) void gemm1_kernel(
    const unsigned short* __restrict__ xn,
    const unsigned short* __restrict__ w1b,
    const float* __restrict__ b1,
    unsigned short* __restrict__ u)
{
    __shared__ __align__(16) unsigned char lds[131072];
    const int tid  = threadIdx.x;
    const int lane = tid & 63;
    const int wv   = tid >> 6;
    const int wm   = wv >> 2;   // 0..1
    const int wn   = wv & 3;    // 0..3

    const int bid = blockIdx.x;                 // nwg = 1024
    const int sw  = (bid & 7) * 128 + (bid >> 3);
    const int jb  = sw & 7;
    const int m0  = (sw >> 3) * 256;

    const unsigned short* agA[4];
    const unsigned short* agB[4];
    {
        const int srow = tid >> 3;
        const int scb  = tid & 7;
        #pragma unroll
        for (int j = 0; j < 4; ++j) {
            int row = j * 64 + srow;
            int kk  = (scb ^ (row & 7)) * 8;
            agA[j] = xn + (size_t)(m0 + row) * D_ + kk;
            int chl  = ((row >> 5) << 4) + (row & 15);
            int wrow = ((row & 16) ? 1024 : 0) + jb * 128 + chl;
            agB[j] = w1b + (size_t)wrow * D_ + kk;
        }
    }

    const int l15 = lane & 15;
    const unsigned kq  = (unsigned)((lane >> 4) << 4);
    const unsigned swx = (unsigned)((l15 & 7) << 4);
    const unsigned rA  = (unsigned)(wm * 128 + l15) * 128;
    const unsigned rB  = 32768u + (unsigned)(wn * 64 + l15) * 128;
    const unsigned bA0[2] = {rA + (kq ^ swx),          rA + (kq ^ swx) + 65536u};
    const unsigned bA1[2] = {rA + ((64u + kq) ^ swx),  rA + ((64u + kq) ^ swx) + 65536u};
    const unsigned bB0[2] = {rB + (kq ^ swx),          rB + (kq ^ swx) + 65536u};
    const unsigned bB1[2] = {rB + ((64u + kq) ^ swx),  rB + ((64u + kq) ^ swx) + 65536u};

    f32x4 acc[8][4];
    #pragma unroll
    for (int i = 0; i < 8; ++i)
        #pragma unroll
        for (int n = 0; n < 4; ++n) acc[i][n] = (f32x4){0.f, 0.f, 0.f, 0.f};

    ISSUE6(0); ISSUE2(0);
    VMCNT(2);
    __builtin_amdgcn_s_barrier();

    // NT = 8 K-tiles
    #pragma unroll 1
    for (int h = 0; h < 3; ++h) {               // kt 0..5
        KTILE2(0, 1, true);
        KTILE2(1, 0, true);
    }
    KTILE2(0, 1, true);                          // kt 6 (stages kt7)
    KTILE2(1, 0, false);                         // kt 7

    // epilogue: SwiGLU, frag-local a/g pairing
    const int rQ = (lane >> 4) * 4;
    #pragma unroll
    for (int p = 0; p < 2; ++p) {
        int ch = jb * 128 + wn * 32 + p * 16 + l15;
        float ba = b1[ch];
        float bg = b1[1024 + ch];
        #pragma unroll
        for (int mf = 0; mf < 8; ++mf) {
            #pragma unroll
            for (int r = 0; r < 4; ++r) {
                float a = acc[mf][2 * p][r] + ba;
                float g = acc[mf][2 * p + 1][r] + bg;
                float sg = g * __builtin_amdgcn_rcpf(1.0f + __expf(-g));
                int row = m0 + wm * 128 + mf * 16 + rQ + r;
                u[(size_t)row * I_ + ch] = f2bf(a * sg);
            }
        }
    }
}

// ---------------- depthwise conv K=31 + bias + PReLU: u bf16 -> v bf16 ----
// Transposed LDS (R12) with quad-row staging: each thread loads 4
// consecutive t-rows (uint4, same 8 channels), packs in-register, writes
// 8 x ds_write_b64 — 24 b64 writes/thread vs 72 b16 (R12-R14). Quads
// cover rows 0..287 with explicit zero-fill (also closes the previous
// uninitialized-LDS read at elements 286/287). Compute = R14 fdot2.
#define SUTS 292
__global__ __launch_bounds__(256, 4) void dwconv_kernel(
    const unsigned short* __restrict__ u, const float* __restrict__ dw,
    const float* __restrict__ dwb, const float* __restrict__ alpha,
    unsigned short* __restrict__ v)
{
    // grid: x = T/256 = 8, y = I/64 = 16, z = B = 16
    __shared__ __align__(8) unsigned short sut[64 * SUTS];   // 37376 B
    const int tid = threadIdx.x;
    const int c0  = blockIdx.y * 64;
    const int b   = blockIdx.z;
    const int t0  = blockIdx.x * 256;

    // stage + transpose: rows r in [0,288) (t = t0-15+r), zero-filled halo
    {
        const int g  = tid & 7;    // col group: channels cc..cc+7
        const int q  = tid >> 3;   // 0..31
        const int cc = g * 8;
        #pragma unroll
        for (int it = 0; it < 3; ++it) {
            int Q = it * 32 + q;               // row quad 0..95
            if (Q < 72) {
                int r0 = Q * 4;
                unsigned short e[4][8];
                #pragma unroll
                for (int dr = 0; dr < 4; ++dr) {
                    int tt = t0 - 15 + r0 + dr;
                    uint4 val = {0u, 0u, 0u, 0u};
                    if (tt >= 0 && tt < T_)
                        val = *(const uint4*)(u + ((size_t)b * T_ + tt) * I_ + c0 + cc);
                    *(uint4*)e[dr] = val;
                }
                #pragma unroll
                for (int jj = 0; jj < 8; ++jj) {
                    uint2 pk;
                    pk.x = (uint32_t)e[0][jj] | ((uint32_t)e[1][jj] << 16);
                    pk.y = (uint32_t)e[2][jj] | ((uint32_t)e[3][jj] << 16);
                    *(uint2*)(&sut[(cc + jj) * SUTS + r0]) = pk;
                }
            }
        }
    }
    __syncthreads();

    const int c  = tid & 63;
    const int tb = (tid >> 6) * 64;   // 64 outputs per thread

    // dw -> f16 pairs (16 pairs; last = (dw[30], 0))
    f16x2 dwp[16];
    {
        const float* dwc = dw + (size_t)(c0 + c) * K_;
        #pragma unroll
        for (int m = 0; m < 15; ++m)
            dwp[m] = __builtin_amdgcn_cvt_pkrtz(dwc[2 * m], dwc[2 * m + 1]);
        dwp[15] = __builtin_amdgcn_cvt_pkrtz(dwc[30], 0.0f);
    }
    const float bia = dwb[c0 + c], al = alpha[c0 + c];

    const unsigned short* srow = sut + c * SUTS;
    unsigned short* vb = v + ((size_t)b * T_ + t0 + tb) * I_ + c0 + c;

    #pragma unroll
    for (int chk = 0; chk < 4; ++chk) {
        const int o = tb + chk * 16;           // window j in [o, o+48)
        uint32_t pkEu[24];
        #pragma unroll
        for (int q = 0; q < 12; ++q) {
            uint2 d = *(const uint2*)(srow + o + q * 4);
            union { uint32_t u; float f; } lo, hi;
            lo.u = d.x << 16; hi.u = d.x & 0xFFFF0000u;
            pkEu[2 * q] = __builtin_bit_cast(uint32_t,
                __builtin_amdgcn_cvt_pkrtz(lo.f, hi.f));
            lo.u = d.y << 16; hi.u = d.y & 0xFFFF0000u;
            pkEu[2 * q + 1] = __builtin_bit_cast(uint32_t,
                __builtin_amdgcn_cvt_pkrtz(lo.f, hi.f));
        }
        uint32_t pkOu[23];
        #pragma unroll
        for (int q = 0; q < 23; ++q)
            pkOu[q] = (pkEu[q] >> 16) | (pkEu[q + 1] << 16);

        #pragma unroll
        for (int i = 0; i < 16; ++i) {
            float acc = bia;
            const int e = i >> 1;
            #pragma unroll
            for (int m = 0; m < 16; ++m) {
                uint32_t wv = (i & 1) ? pkOu[e + m] : pkEu[e + m];
                acc = __builtin_amdgcn_fdot2(
                    __builtin_bit_cast(f16x2, wv), dwp[m], acc, false);
            }
            float ov = acc > 0.f ? acc : al * acc;
            vb[(size_t)(chk * 16 + i) * I_] = f2bf(ov);
        }
    }
}

// ---------------- GEMM2: v[32768,1024] x w2b^T + b2 -> out fp32 [32768,512] ----------------
__global__ __launch_bounds__(512, 2) void gemm2_kernel(
    const unsigned short* __restrict__ v,
    const unsigned short* __restrict__ w2b,
    const float* __restrict__ b2,
    float* __restrict__ out)
{
    __shared__ __align__(16) unsigned char lds[131072];
    const int tid  = threadIdx.x;
    const int lane = tid & 63;
    const int wv   = tid >> 6;
    const int wm   = wv >> 2;
    const int wn   = wv & 3;

    const int bid = blockIdx.x;                 // 256 blocks
    const int sw  = (bid & 7) * 32 + (bid >> 3);
    const int n0  = (sw & 1) * 256;
    const int m0  = (sw >> 1) * 256;

    const unsigned short* agA[4];
    const unsigned short* agB[4];
    {
        const int srow = tid >> 3;
        const int scb  = tid & 7;
        #pragma unroll
        for (int j = 0; j < 4; ++j) {
            int row = j * 64 + srow;
            int kk  = (scb ^ (row & 7)) * 8;
            agA[j] = v   + (size_t)(m0 + row) * I_ + kk;
            agB[j] = w2b + (size_t)(n0 + row) * I_ + kk;
        }
    }

    const int l15 = lane & 15;
    const unsigned kq  = (unsigned)((lane >> 4) << 4);
    const unsigned swx = (unsigned)((l15 & 7) << 4);
    const unsigned rA  = (unsigned)(wm * 128 + l15) * 128;
    const unsigned rB  = 32768u + (unsigned)(wn * 64 + l15) * 128;
    const unsigned bA0[2] = {rA + (kq ^ swx),          rA + (kq ^ swx) + 65536u};
    const unsigned bA1[2] = {rA + ((64u + kq) ^ swx),  rA + ((64u + kq) ^ swx) + 65536u};
    const unsigned bB0[2] = {rB + (kq ^ swx),          rB + (kq ^ swx) + 65536u};
    const unsigned bB1[2] = {rB + ((64u + kq) ^ swx),  rB + ((64u + kq) ^ swx) + 65536u};

    f32x4 acc[8][4];
    #pragma unroll
    for (int i = 0; i < 8; ++i)
        #pragma unroll
        for (int n = 0; n < 4; ++n) acc[i][n] = (f32x4){0.f, 0.f, 0.f, 0.f};

    ISSUE6(0); ISSUE2(0);
    VMCNT(2);
    __builtin_amdgcn_s_barrier();

    // NT = 16 K-tiles
    #pragma unroll 1
    for (int h = 0; h < 7; ++h) {               // kt 0..13
        KTILE2(0, 1, true);
        KTILE2(1, 0, true);
    }
    KTILE2(0, 1, true);                          // kt 14
    KTILE2(1, 0, false);                         // kt 15

    const int rQ = (lane >> 4) * 4;
    #pragma unroll
    for (int nf = 0; nf < 4; ++nf) {
        int col = n0 + wn * 64 + nf * 16 + l15;
        float bb = b2[col];
        #pragma unroll
        for (int mf = 0; mf < 8; ++mf) {
            #pragma unroll
            for (int r = 0; r < 4; ++r) {
                int row = m0 + wm * 128 + mf * 16 + rQ + r;
                out[(size_t)row * D_ + col] = acc[mf][nf][r] + bb;
            }
        }
    }
}

extern "C" void kernel_launch(void* const* d_in, const int* in_sizes, int n_in,
                              void* d_out, int out_size, void* d_ws, size_t ws_size,
                              hipStream_t stream) {
    const float* x     = (const float*)d_in[0];
    const float* ln_g  = (const float*)d_in[1];
    const float* ln_b  = (const float*)d_in[2];
    const float* w1    = (const float*)d_in[3];
    const float* b1    = (const float*)d_in[4];
    const float* dw    = (const float*)d_in[5];
    const float* dwb   = (const float*)d_in[6];
    const float* alpha = (const float*)d_in[7];
    const float* w2    = (const float*)d_in[8];
    const float* b2    = (const float*)d_in[9];
    float* out = (float*)d_out;

    char* ws = (char*)d_ws;
    unsigned short* xn  = (unsigned short*)(ws);                 // 32 MB
    unsigned short* u   = (unsigned short*)(ws + 33554432);      // 64 MB
    unsigned short* v   = (unsigned short*)(ws + 100663296);     // 64 MB
    unsigned short* w1b = (unsigned short*)(ws + 167772160);     // 2 MB
    unsigned short* w2b = (unsigned short*)(ws + 169869312);     // 1 MB

    ln_prep_kernel<<<12288, 256, 0, stream>>>(x, ln_g, ln_b, xn, w1, w2, w1b, w2b);
    gemm1_kernel<<<(M_ / 256) * (I_ / 128), 512, 0, stream>>>(xn, w1b, b1, u);  // 1024
    dim3 gc(T_ / 256, I_ / 64, B_);           // (8, 16, 16)
    dwconv_kernel<<<gc, 256, 0, stream>>>(u, dw, dwb, alpha, v);
    gemm2_kernel<<<256, 512, 0, stream>>>(v, w2b, b2, out);
}

// Round 17
// 171.906 us; speedup vs baseline: 1.0297x; 1.0239x over previous
//
#include <hip/hip_runtime.h>
#include <hip/hip_bf16.h>
#include <stdint.h>

// Problem dims
#define B_  16
#define T_  2048
#define D_  512
#define I_  1024
#define K_  31
#define M_  (B_ * T_)   // 32768

typedef __attribute__((ext_vector_type(8))) __bf16 bf16x8;
typedef __attribute__((ext_vector_type(4))) float  f32x4;
typedef __fp16 f16x2 __attribute__((ext_vector_type(2)));

__device__ __forceinline__ unsigned short f2bf(float f) {
    union { float f; uint32_t u; } v; v.f = f;
    uint32_t u = v.u;
    uint32_t r = (u + 0x7FFFu + ((u >> 16) & 1u)) >> 16;
    return (unsigned short)r;
}
__device__ __forceinline__ unsigned short f2h(float f) {
    union { __fp16 h[2]; unsigned short s[2]; } cv;
    cv.h[0] = (__fp16)f;
    return cv.s[0];
}

__device__ __forceinline__ void gload_lds16(const void* g, void* l) {
    __builtin_amdgcn_global_load_lds(
        (const __attribute__((address_space(1))) unsigned int*)g,
        (__attribute__((address_space(3))) unsigned int*)l, 16, 0, 0);
}

// ---------------- fused: LayerNorm (bid < 8192) + weight cast (bid >= 8192)
__global__ __launch_bounds__(256) void ln_prep_kernel(
    const float* __restrict__ x, const float* __restrict__ gam,
    const float* __restrict__ bet, unsigned short* __restrict__ xn,
    const float* __restrict__ w1, const float* __restrict__ w2,
    unsigned short* __restrict__ w1b, unsigned short* __restrict__ w2b)
{
    if (blockIdx.x >= 8192) {
        int i = (blockIdx.x - 8192) * 256 + threadIdx.x;
        const int n1 = 2 * I_ * D_;   // 1048576
        const int n2 = D_ * I_;       // 524288
        if (i < n1) w1b[i] = f2bf(w1[i]);
        if (i < n2) w2b[i] = f2bf(w2[i]);
        return;
    }
    int row  = blockIdx.x * 4 + (threadIdx.x >> 6);
    int lane = threadIdx.x & 63;
    const float* xr = x + (size_t)row * D_ + lane * 8;
    float4 a0 = *(const float4*)xr;
    float4 a1 = *(const float4*)(xr + 4);
    float xs[8] = {a0.x, a0.y, a0.z, a0.w, a1.x, a1.y, a1.z, a1.w};

    float s = xs[0]+xs[1]+xs[2]+xs[3]+xs[4]+xs[5]+xs[6]+xs[7];
    #pragma unroll
    for (int off = 32; off; off >>= 1) s += __shfl_xor(s, off);
    float mu = s * (1.0f / D_);

    float q = 0.f;
    #pragma unroll
    for (int j = 0; j < 8; ++j) { float d = xs[j] - mu; q += d * d; }
    #pragma unroll
    for (int off = 32; off; off >>= 1) q += __shfl_xor(q, off);
    float rstd = rsqrtf(q * (1.0f / D_) + 1e-5f);

    float4 g0 = *(const float4*)(gam + lane * 8);
    float4 g1 = *(const float4*)(gam + lane * 8 + 4);
    float4 e0 = *(const float4*)(bet + lane * 8);
    float4 e1 = *(const float4*)(bet + lane * 8 + 4);
    float gs[8] = {g0.x, g0.y, g0.z, g0.w, g1.x, g1.y, g1.z, g1.w};
    float bs[8] = {e0.x, e0.y, e0.z, e0.w, e1.x, e1.y, e1.z, e1.w};

    unsigned short o[8];
    #pragma unroll
    for (int j = 0; j < 8; ++j) o[j] = f2bf((xs[j] - mu) * rstd * gs[j] + bs[j]);
    uint4 pk;
    pk.x = (uint32_t)o[0] | ((uint32_t)o[1] << 16);
    pk.y = (uint32_t)o[2] | ((uint32_t)o[3] << 16);
    pk.z = (uint32_t)o[4] | ((uint32_t)o[5] << 16);
    pk.w = (uint32_t)o[6] | ((uint32_t)o[7] << 16);
    *(uint4*)(xn + (size_t)row * D_ + lane * 8) = pk;
}

// ======================================================================
// 256x256-class GEMM engine, 2 barriers per K-tile (KTILE2) — R6-proven.
// FROZEN (R7-R9: every reordering regressed 8-20%).
// ======================================================================

#define VMCNT(n) asm volatile("s_waitcnt vmcnt(" #n ")" ::: "memory")

#define RD(base, idx) (*(const bf16x8*)(lds + (base) + (idx) * 2048))
#define MF(m, n, a, b) \
    acc[m][n] = __builtin_amdgcn_mfma_f32_16x16x32_bf16(a, b, acc[m][n], 0, 0, 0)
#define MFQ(MB, x0, x1, x2, x3, c0, c1, c2, c3) do { \
    MF(MB+0,0,x0,c0); MF(MB+0,1,x0,c1); MF(MB+0,2,x0,c2); MF(MB+0,3,x0,c3); \
    MF(MB+1,0,x1,c0); MF(MB+1,1,x1,c1); MF(MB+1,2,x1,c2); MF(MB+1,3,x1,c3); \
    MF(MB+2,0,x2,c0); MF(MB+2,1,x2,c1); MF(MB+2,2,x2,c2); MF(MB+2,3,x2,c3); \
    MF(MB+3,0,x3,c0); MF(MB+3,1,x3,c1); MF(MB+3,2,x3,c2); MF(MB+3,3,x3,c3); \
} while (0)

#define ISSUE_A(j, c) do { \
    gload_lds16(agA[j], lds + (c) * 65536 + tid * 16 + (j) * 8192); \
    agA[j] += 64; } while (0)
#define ISSUE_B(j, c) do { \
    gload_lds16(agB[j], lds + (c) * 65536 + 32768 + tid * 16 + (j) * 8192); \
    agB[j] += 64; } while (0)
#define ISSUE6(c) do { ISSUE_B(0,c); ISSUE_B(1,c); ISSUE_B(2,c); ISSUE_B(3,c); \
                       ISSUE_A(0,c); ISSUE_A(2,c); } while (0)
#define ISSUE2(c) do { ISSUE_A(1,c); ISSUE_A(3,c); } while (0)

#define LGKM_SCHED() do { \
    asm volatile("s_waitcnt lgkmcnt(0)" ::: "memory"); \
    __builtin_amdgcn_sched_barrier(0); } while (0)

#define KTILE2(CUR, NXT, DOISS) do { \
    bf16x8 b0,b1,b2,b3, x0,x1,x2,x3; \
    b0 = RD(bB0[CUR],0); b1 = RD(bB0[CUR],1); b2 = RD(bB0[CUR],2); b3 = RD(bB0[CUR],3); \
    x0 = RD(bA0[CUR],0); x1 = RD(bA0[CUR],1); x2 = RD(bA0[CUR],2); x3 = RD(bA0[CUR],3); \
    if (DOISS) { ISSUE6(NXT); } \
    __builtin_amdgcn_s_setprio(1); \
    MFQ(0, x0,x1,x2,x3, b0,b1,b2,b3); \
    __builtin_amdgcn_s_setprio(0); \
    LGKM_SCHED(); \
    if (DOISS) { VMCNT(6); } else { VMCNT(0); } \
    __builtin_amdgcn_s_barrier(); \
    x0 = RD(bA0[CUR],4); x1 = RD(bA0[CUR],5); x2 = RD(bA0[CUR],6); x3 = RD(bA0[CUR],7); \
    if (DOISS) { ISSUE2(NXT); } \
    __builtin_amdgcn_s_setprio(1); \
    MFQ(4, x0,x1,x2,x3, b0,b1,b2,b3); \
    __builtin_amdgcn_s_setprio(0); \
    b0 = RD(bB1[CUR],0); b1 = RD(bB1[CUR],1); b2 = RD(bB1[CUR],2); b3 = RD(bB1[CUR],3); \
    x0 = RD(bA1[CUR],0); x1 = RD(bA1[CUR],1); x2 = RD(bA1[CUR],2); x3 = RD(bA1[CUR],3); \
    __builtin_amdgcn_s_setprio(1); \
    MFQ(0, x0,x1,x2,x3, b0,b1,b2,b3); \
    __builtin_amdgcn_s_setprio(0); \
    x0 = RD(bA1[CUR],4); x1 = RD(bA1[CUR],5); x2 = RD(bA1[CUR],6); x3 = RD(bA1[CUR],7); \
    __builtin_amdgcn_s_setprio(1); \
    MFQ(4, x0,x1,x2,x3, b0,b1,b2,b3); \
    __builtin_amdgcn_s_setprio(0); \
    LGKM_SCHED(); \
    if (DOISS) { VMCNT(2); } \
    __builtin_amdgcn_s_barrier(); \
} while (0)

// ---------------- GEMM1: 1024 blocks, one 256-row x 128-channel tile each.
// Output u stored as FP16 (dwconv consumes packed-f16 pairs directly).
__global__ __launch_bounds__(512, 2) void gemm1_kernel(
    const unsigned short* __restrict__ xn,
    const unsigned short* __restrict__ w1b,
    const float* __restrict__ b1,
    unsigned short* __restrict__ u)
{
    __shared__ __align__(16) unsigned char lds[131072];
    const int tid  = threadIdx.x;
    const int lane = tid & 63;
    const int wv   = tid >> 6;
    const int wm   = wv >> 2;   // 0..1
    const int wn   = wv & 3;    // 0..3

    const int bid = blockIdx.x;                 // nwg = 1024
    const int sw  = (bid & 7) * 128 + (bid >> 3);
    const int jb  = sw & 7;
    const int m0  = (sw >> 3) * 256;

    const unsigned short* agA[4];
    const unsigned short* agB[4];
    {
        const int srow = tid >> 3;
        const int scb  = tid & 7;
        #pragma unroll
        for (int j = 0; j < 4; ++j) {
            int row = j * 64 + srow;
            int kk  = (scb ^ (row & 7)) * 8;
            agA[j] = xn + (size_t)(m0 + row) * D_ + kk;
            int chl  = ((row >> 5) << 4) + (row & 15);
            int wrow = ((row & 16) ? 1024 : 0) + jb * 128 + chl;
            agB[j] = w1b + (size_t)wrow * D_ + kk;
        }
    }

    const int l15 = lane & 15;
    const unsigned kq  = (unsigned)((lane >> 4) << 4);
    const unsigned swx = (unsigned)((l15 & 7) << 4);
    const unsigned rA  = (unsigned)(wm * 128 + l15) * 128;
    const unsigned rB  = 32768u + (unsigned)(wn * 64 + l15) * 128;
    const unsigned bA0[2] = {rA + (kq ^ swx),          rA + (kq ^ swx) + 65536u};
    const unsigned bA1[2] = {rA + ((64u + kq) ^ swx),  rA + ((64u + kq) ^ swx) + 65536u};
    const unsigned bB0[2] = {rB + (kq ^ swx),          rB + (kq ^ swx) + 65536u};
    const unsigned bB1[2] = {rB + ((64u + kq) ^ swx),  rB + ((64u + kq) ^ swx) + 65536u};

    f32x4 acc[8][4];
    #pragma unroll
    for (int i = 0; i < 8; ++i)
        #pragma unroll
        for (int n = 0; n < 4; ++n) acc[i][n] = (f32x4){0.f, 0.f, 0.f, 0.f};

    ISSUE6(0); ISSUE2(0);
    VMCNT(2);
    __builtin_amdgcn_s_barrier();

    // NT = 8 K-tiles
    #pragma unroll 1
    for (int h = 0; h < 3; ++h) {               // kt 0..5
        KTILE2(0, 1, true);
        KTILE2(1, 0, true);
    }
    KTILE2(0, 1, true);                          // kt 6 (stages kt7)
    KTILE2(1, 0, false);                         // kt 7

    // epilogue: SwiGLU, frag-local a/g pairing; u stored as f16
    const int rQ = (lane >> 4) * 4;
    #pragma unroll
    for (int p = 0; p < 2; ++p) {
        int ch = jb * 128 + wn * 32 + p * 16 + l15;
        float ba = b1[ch];
        float bg = b1[1024 + ch];
        #pragma unroll
        for (int mf = 0; mf < 8; ++mf) {
            #pragma unroll
            for (int r = 0; r < 4; ++r) {
                float a = acc[mf][2 * p][r] + ba;
                float g = acc[mf][2 * p + 1][r] + bg;
                float sg = g * __builtin_amdgcn_rcpf(1.0f + __expf(-g));
                int row = m0 + wm * 128 + mf * 16 + rQ + r;
                u[(size_t)row * I_ + ch] = f2h(a * sg);
            }
        }
    }
}

// ---------------- depthwise conv K=31 + bias + PReLU: u f16 -> v bf16 ----
// Transposed LDS (R12 geometry). u is f16 -> LDS dwords ARE the packed
// even-phase pairs (no cvt needed; deletes 24 cvt_pkrtz/chunk). fdot2 with
// 2-way split accumulator (halves dependent-chain latency at low occ).
#define SUTS 292
__global__ __launch_bounds__(256, 4) void dwconv_kernel(
    const unsigned short* __restrict__ u, const float* __restrict__ dw,
    const float* __restrict__ dwb, const float* __restrict__ alpha,
    unsigned short* __restrict__ v)
{
    // grid: x = T/256 = 8, y = I/64 = 16, z = B = 16
    __shared__ __align__(8) unsigned short sut[64 * SUTS];   // 37376 B
    const int tid = threadIdx.x;
    const int c0  = blockIdx.y * 64;
    const int b   = blockIdx.z;
    const int t0  = blockIdx.x * 256;

    // stage + transpose: j in [0,286), t = t0-15+j, zero-filled halo
    #pragma unroll
    for (int it = 0; it < 9; ++it) {
        int r = it * 32 + (tid >> 3);
        if (r < 286) {
            int tt = t0 - 15 + r;
            int cc = (tid & 7) * 8;
            uint4 val = {0u, 0u, 0u, 0u};
            if (tt >= 0 && tt < T_)
                val = *(const uint4*)(u + ((size_t)b * T_ + tt) * I_ + c0 + cc);
            unsigned short e[8];
            *(uint4*)e = val;
            #pragma unroll
            for (int jj = 0; jj < 8; ++jj)
                sut[(cc + jj) * SUTS + r] = e[jj];
        }
    }
    // zero rows 286..287 (read by window tails)
    if (tid < 64) {
        sut[tid * SUTS + 286] = 0;
        sut[tid * SUTS + 287] = 0;
    }
    __syncthreads();

    const int c  = tid & 63;
    const int tb = (tid >> 6) * 64;   // 64 outputs per thread

    // dw -> f16 pairs (16 pairs; last = (dw[30], 0))
    f16x2 dwp[16];
    {
        const float* dwc = dw + (size_t)(c0 + c) * K_;
        #pragma unroll
        for (int m = 0; m < 15; ++m)
            dwp[m] = __builtin_amdgcn_cvt_pkrtz(dwc[2 * m], dwc[2 * m + 1]);
        dwp[15] = __builtin_amdgcn_cvt_pkrtz(dwc[30], 0.0f);
    }
    const float bia = dwb[c0 + c], al = alpha[c0 + c];

    const unsigned short* srow = sut + c * SUTS;
    unsigned short* vb = v + ((size_t)b * T_ + t0 + tb) * I_ + c0 + c;

    #pragma unroll
    for (int chk = 0; chk < 4; ++chk) {
        const int o = tb + chk * 16;           // window j in [o, o+48)
        // u already f16: LDS dwords are the even-phase packed pairs
        uint32_t pkEu[24];
        #pragma unroll
        for (int q = 0; q < 12; ++q) {
            uint2 d = *(const uint2*)(srow + o + q * 4);
            pkEu[2 * q]     = d.x;
            pkEu[2 * q + 1] = d.y;
        }
        // odd-phase pairs: (w[2q+1], w[2q+2])
        uint32_t pkOu[23];
        #pragma unroll
        for (int q = 0; q < 23; ++q)
            pkOu[q] = (pkEu[q] >> 16) | (pkEu[q + 1] << 16);

        #pragma unroll
        for (int i = 0; i < 16; ++i) {
            const int e = i >> 1;
            float acc0 = bia, acc1 = 0.f;
            #pragma unroll
            for (int m = 0; m < 8; ++m) {
                uint32_t w0 = (i & 1) ? pkOu[e + 2 * m]     : pkEu[e + 2 * m];
                uint32_t w1 = (i & 1) ? pkOu[e + 2 * m + 1] : pkEu[e + 2 * m + 1];
                acc0 = __builtin_amdgcn_fdot2(
                    __builtin_bit_cast(f16x2, w0), dwp[2 * m], acc0, false);
                acc1 = __builtin_amdgcn_fdot2(
                    __builtin_bit_cast(f16x2, w1), dwp[2 * m + 1], acc1, false);
            }
            float acc = acc0 + acc1;
            float ov = acc > 0.f ? acc : al * acc;
            vb[(size_t)(chk * 16 + i) * I_] = f2bf(ov);
        }
    }
}

// ---------------- GEMM2: v[32768,1024] x w2b^T + b2 -> out fp32 [32768,512] ----------------
__global__ __launch_bounds__(512, 2) void gemm2_kernel(
    const unsigned short* __restrict__ v,
    const unsigned short* __restrict__ w2b,
    const float* __restrict__ b2,
    float* __restrict__ out)
{
    __shared__ __align__(16) unsigned char lds[131072];
    const int tid  = threadIdx.x;
    const int lane = tid & 63;
    const int wv   = tid >> 6;
    const int wm   = wv >> 2;
    const int wn   = wv & 3;

    const int bid = blockIdx.x;                 // 256 blocks
    const int sw  = (bid & 7) * 32 + (bid >> 3);
    const int n0  = (sw & 1) * 256;
    const int m0  = (sw >> 1) * 256;

    const unsigned short* agA[4];
    const unsigned short* agB[4];
    {
        const int srow = tid >> 3;
        const int scb  = tid & 7;
        #pragma unroll
        for (int j = 0; j < 4; ++j) {
            int row = j * 64 + srow;
            int kk  = (scb ^ (row & 7)) * 8;
            agA[j] = v   + (size_t)(m0 + row) * I_ + kk;
            agB[j] = w2b + (size_t)(n0 + row) * I_ + kk;
        }
    }

    const int l15 = lane & 15;
    const unsigned kq  = (unsigned)((lane >> 4) << 4);
    const unsigned swx = (unsigned)((l15 & 7) << 4);
    const unsigned rA  = (unsigned)(wm * 128 + l15) * 128;
    const unsigned rB  = 32768u + (unsigned)(wn * 64 + l15) * 128;
    const unsigned bA0[2] = {rA + (kq ^ swx),          rA + (kq ^ swx) + 65536u};
    const unsigned bA1[2] = {rA + ((64u + kq) ^ swx),  rA + ((64u + kq) ^ swx) + 65536u};
    const unsigned bB0[2] = {rB + (kq ^ swx),          rB + (kq ^ swx) + 65536u};
    const unsigned bB1[2] = {rB + ((64u + kq) ^ swx),  rB + ((64u + kq) ^ swx) + 65536u};

    f32x4 acc[8][4];
    #pragma unroll
    for (int i = 0; i < 8; ++i)
        #pragma unroll
        for (int n = 0; n < 4; ++n) acc[i][n] = (f32x4){0.f, 0.f, 0.f, 0.f};

    ISSUE6(0); ISSUE2(0);
    VMCNT(2);
    __builtin_amdgcn_s_barrier();

    // NT = 16 K-tiles
    #pragma unroll 1
    for (int h = 0; h < 7; ++h) {               // kt 0..13
        KTILE2(0, 1, true);
        KTILE2(1, 0, true);
    }
    KTILE2(0, 1, true);                          // kt 14
    KTILE2(1, 0, false);                         // kt 15

    const int rQ = (lane >> 4) * 4;
    #pragma unroll
    for (int nf = 0; nf < 4; ++nf) {
        int col = n0 + wn * 64 + nf * 16 + l15;
        float bb = b2[col];
        #pragma unroll
        for (int mf = 0; mf < 8; ++mf) {
            #pragma unroll
            for (int r = 0; r < 4; ++r) {
                int row = m0 + wm * 128 + mf * 16 + rQ + r;
                out[(size_t)row * D_ + col] = acc[mf][nf][r] + bb;
            }
        }
    }
}

extern "C" void kernel_launch(void* const* d_in, const int* in_sizes, int n_in,
                              void* d_out, int out_size, void* d_ws, size_t ws_size,
                              hipStream_t stream) {
    const float* x     = (const float*)d_in[0];
    const float* ln_g  = (const float*)d_in[1];
    const float* ln_b  = (const float*)d_in[2];
    const float* w1    = (const float*)d_in[3];
    const float* b1    = (const float*)d_in[4];
    const float* dw    = (const float*)d_in[5];
    const float* dwb   = (const float*)d_in[6];
    const float* alpha = (const float*)d_in[7];
    const float* w2    = (const float*)d_in[8];
    const float* b2    = (const float*)d_in[9];
    float* out = (float*)d_out;

    char* ws = (char*)d_ws;
    unsigned short* xn  = (unsigned short*)(ws);                 // 32 MB
    unsigned short* u   = (unsigned short*)(ws + 33554432);      // 64 MB (f16)
    unsigned short* v   = (unsigned short*)(ws + 100663296);     // 64 MB (bf16)
    unsigned short* w1b = (unsigned short*)(ws + 167772160);     // 2 MB
    unsigned short* w2b = (unsigned short*)(ws + 169869312);     // 1 MB

    ln_prep_kernel<<<12288, 256, 0, stream>>>(x, ln_g, ln_b, xn, w1, w2, w1b, w2b);
    gemm1_kernel<<<(M_ / 256) * (I_ / 128), 512, 0, stream>>>(xn, w1b, b1, u);  // 1024
    dim3 gc(T_ / 256, I_ / 64, B_);           // (8, 16, 16)
    dwconv_kernel<<<gc, 256, 0, stream>>>(u, dw, dwb, alpha, v);
    gemm2_kernel<<<256, 512, 0, stream>>>(v, w2b, b2, out);
}